// Round 1
// baseline (1266.577 us; speedup 1.0000x reference)
//
#include <hip/hip_runtime.h>
#include <stdint.h>

// Problem sizes (fixed by reference)
#define T_DIM 4096
#define B_DIM 8
#define M_ROWS (T_DIM * B_DIM)   // 32768
#define I_DIM 256
#define H_DIM 512
#define C_DIM 1024
#define O_DIM 512

// GEMM tiling
#define BM 64
#define BN 64
#define BK 32
#define TM 4
#define TN 4
#define PAD 4   // LDS pad (floats) keeps float4 alignment (68 % 4 == 0) and spreads banks

// ---------------------------------------------------------------------------
// GEMM1: Hout[m,n] = relu( sum_k X[m,k] * W1[n,k] + b1[n] )
// X: [M_ROWS, I_DIM] row-major, W1: [H_DIM, I_DIM] row-major (i.e. B^T layout)
// ---------------------------------------------------------------------------
__global__ __launch_bounds__(256)
void gemm1_relu(const float* __restrict__ X, const float* __restrict__ W1,
                const float* __restrict__ b1, float* __restrict__ Hout) {
    __shared__ float As[BK][BM + PAD];
    __shared__ float Bs[BK][BN + PAD];
    const int tid = threadIdx.x;
    const int tx = tid & 15;   // N dim
    const int ty = tid >> 4;   // M dim
    const int mBase = blockIdx.y * BM;
    const int nBase = blockIdx.x * BN;

    float acc[TM][TN] = {};

    for (int k0 = 0; k0 < I_DIM; k0 += BK) {
        // 64 rows x 8 float4 = 512 float4 per tile; 256 threads -> 2 each
        #pragma unroll
        for (int l = 0; l < 2; ++l) {
            int f = tid + l * 256;
            int row = f >> 3, kv = (f & 7) << 2;
            float4 v = *(const float4*)(X + (size_t)(mBase + row) * I_DIM + k0 + kv);
            As[kv + 0][row] = v.x; As[kv + 1][row] = v.y;
            As[kv + 2][row] = v.z; As[kv + 3][row] = v.w;
        }
        #pragma unroll
        for (int l = 0; l < 2; ++l) {
            int f = tid + l * 256;
            int row = f >> 3, kv = (f & 7) << 2;
            float4 v = *(const float4*)(W1 + (size_t)(nBase + row) * I_DIM + k0 + kv);
            Bs[kv + 0][row] = v.x; Bs[kv + 1][row] = v.y;
            Bs[kv + 2][row] = v.z; Bs[kv + 3][row] = v.w;
        }
        __syncthreads();
        #pragma unroll
        for (int k = 0; k < BK; ++k) {
            float a[TM], b[TN];
            *(float4*)a = *(const float4*)&As[k][ty * TM];
            *(float4*)b = *(const float4*)&Bs[k][tx * TN];
            #pragma unroll
            for (int i = 0; i < TM; ++i)
                #pragma unroll
                for (int j = 0; j < TN; ++j)
                    acc[i][j] = fmaf(a[i], b[j], acc[i][j]);
        }
        __syncthreads();
    }

    #pragma unroll
    for (int i = 0; i < TM; ++i) {
        int m = mBase + ty * TM + i;
        float4 o;
        float* po = &o.x;
        #pragma unroll
        for (int j = 0; j < TN; ++j) {
            float v = acc[i][j] + b1[nBase + tx * TN + j];
            po[j] = v > 0.f ? v : 0.f;
        }
        *(float4*)(Hout + (size_t)m * H_DIM + nBase + tx * TN) = o;
    }
}

// Monotone packing: larger packed <=> (larger value, then smaller col index)
__device__ inline unsigned long long packvi(float v, int col) {
    unsigned u = __float_as_uint(v);
    u = (u & 0x80000000u) ? ~u : (u | 0x80000000u);
    return ((unsigned long long)u << 32) | (unsigned)(~col);
}

// ---------------------------------------------------------------------------
// GEMM2 + per-tile argmax: pre-relu c[m,n] = sum_k H[m,k]*W2[n,k] + b2[n]
// Writes packed per-row tile-maxima: part[m*16 + tileN]
// ---------------------------------------------------------------------------
__global__ __launch_bounds__(256)
void gemm2_argmax(const float* __restrict__ Hin, const float* __restrict__ W2,
                  const float* __restrict__ b2, unsigned long long* __restrict__ part) {
    __shared__ float As[BK][BM + PAD];
    __shared__ float Bs[BK][BN + PAD];
    __shared__ unsigned long long red[BM][16];
    const int tid = threadIdx.x;
    const int tx = tid & 15;
    const int ty = tid >> 4;
    const int mBase = blockIdx.y * BM;
    const int nBase = blockIdx.x * BN;

    float acc[TM][TN] = {};

    for (int k0 = 0; k0 < H_DIM; k0 += BK) {
        #pragma unroll
        for (int l = 0; l < 2; ++l) {
            int f = tid + l * 256;
            int row = f >> 3, kv = (f & 7) << 2;
            float4 v = *(const float4*)(Hin + (size_t)(mBase + row) * H_DIM + k0 + kv);
            As[kv + 0][row] = v.x; As[kv + 1][row] = v.y;
            As[kv + 2][row] = v.z; As[kv + 3][row] = v.w;
        }
        #pragma unroll
        for (int l = 0; l < 2; ++l) {
            int f = tid + l * 256;
            int row = f >> 3, kv = (f & 7) << 2;
            float4 v = *(const float4*)(W2 + (size_t)(nBase + row) * H_DIM + k0 + kv);
            Bs[kv + 0][row] = v.x; Bs[kv + 1][row] = v.y;
            Bs[kv + 2][row] = v.z; Bs[kv + 3][row] = v.w;
        }
        __syncthreads();
        #pragma unroll
        for (int k = 0; k < BK; ++k) {
            float a[TM], b[TN];
            *(float4*)a = *(const float4*)&As[k][ty * TM];
            *(float4*)b = *(const float4*)&Bs[k][tx * TN];
            #pragma unroll
            for (int i = 0; i < TM; ++i)
                #pragma unroll
                for (int j = 0; j < TN; ++j)
                    acc[i][j] = fmaf(a[i], b[j], acc[i][j]);
        }
        __syncthreads();
    }

    // per-thread argmax over its TN columns, per row
    #pragma unroll
    for (int i = 0; i < TM; ++i) {
        float bv = -3.4e38f; int bc = 0;
        #pragma unroll
        for (int j = 0; j < TN; ++j) {
            int col = nBase + tx * TN + j;
            float v = acc[i][j] + b2[col];
            if (v > bv) { bv = v; bc = col; }   // strict > keeps smallest col on ties
        }
        red[ty * TM + i][tx] = packvi(bv, bc);
    }
    __syncthreads();
    if (tid < BM) {
        unsigned long long best = red[tid][0];
        #pragma unroll
        for (int t = 1; t < 16; ++t) {
            unsigned long long p = red[tid][t];
            if (p > best) best = p;
        }
        part[(size_t)(mBase + tid) * 16 + blockIdx.x] = best;
    }
}

// Reduce 16 tile-partials per row -> jstar (handles all-nonpositive -> idx 0)
__global__ __launch_bounds__(256)
void argmax_reduce(const unsigned long long* __restrict__ part, int* __restrict__ jstar) {
    int m = blockIdx.x * blockDim.x + threadIdx.x;
    if (m >= M_ROWS) return;
    const unsigned long long* p = part + (size_t)m * 16;
    unsigned long long best = p[0];
    #pragma unroll
    for (int t = 1; t < 16; ++t) {
        unsigned long long q = p[t];
        if (q > best) best = q;
    }
    unsigned u = (unsigned)(best >> 32);
    float v = (u & 0x80000000u) ? __uint_as_float(u ^ 0x80000000u)
                                : __uint_as_float(~u);
    int col = (int)(~(unsigned)best) & (C_DIM - 1);
    jstar[m] = (v > 0.f) ? col : 0;   // max<=0 => relu'd c all zero => top_k picks 0
}

// ---------------------------------------------------------------------------
// LS[j, o] = log_softmax_o( Wo[o, j] + bo[o] ), one block per j
// ---------------------------------------------------------------------------
__global__ __launch_bounds__(256)
void ls_table(const float* __restrict__ Wo, const float* __restrict__ bo,
              float* __restrict__ LS) {
    const int j = blockIdx.x;
    const int t = threadIdx.x;
    __shared__ float sred[4];

    float l0 = Wo[(size_t)t * C_DIM + j] + bo[t];
    float l1 = Wo[(size_t)(t + 256) * C_DIM + j] + bo[t + 256];

    float mx = fmaxf(l0, l1);
    #pragma unroll
    for (int off = 1; off < 64; off <<= 1)
        mx = fmaxf(mx, __shfl_xor(mx, off, 64));
    if ((t & 63) == 0) sred[t >> 6] = mx;
    __syncthreads();
    mx = fmaxf(fmaxf(sred[0], sred[1]), fmaxf(sred[2], sred[3]));
    __syncthreads();

    float s = expf(l0 - mx) + expf(l1 - mx);
    #pragma unroll
    for (int off = 1; off < 64; off <<= 1)
        s += __shfl_xor(s, off, 64);
    if ((t & 63) == 0) sred[t >> 6] = s;
    __syncthreads();
    s = sred[0] + sred[1] + sred[2] + sred[3];

    float lse = mx + logf(s);
    LS[(size_t)j * O_DIM + t] = l0 - lse;
    LS[(size_t)j * O_DIM + t + 256] = l1 - lse;
}

// out[m, :] = LS[jstar[m], :], float4 per thread
__global__ __launch_bounds__(256)
void gather_out(const int* __restrict__ jstar, const float* __restrict__ LS,
                float* __restrict__ out) {
    int idx = blockIdx.x * blockDim.x + threadIdx.x;
    int m = idx >> 7;          // 128 float4 per row of 512 floats
    int q = idx & 127;
    float4 v = ((const float4*)LS)[((size_t)jstar[m] << 7) + q];
    ((float4*)out)[idx] = v;
}

extern "C" void kernel_launch(void* const* d_in, const int* in_sizes, int n_in,
                              void* d_out, int out_size, void* d_ws, size_t ws_size,
                              hipStream_t stream) {
    const float* x     = (const float*)d_in[0];
    // d_in[1] = hidden1 dummy, unused
    const float* i2m_w = (const float*)d_in[2];
    const float* i2m_b = (const float*)d_in[3];
    const float* m2h_w = (const float*)d_in[4];
    const float* m2h_b = (const float*)d_in[5];
    const float* h2o_w = (const float*)d_in[6];
    const float* h2o_b = (const float*)d_in[7];
    float* out = (float*)d_out;

    // Workspace layout (d_out doubles as the H buffer: 32768*512 floats exactly)
    char* ws = (char*)d_ws;
    unsigned long long* part = (unsigned long long*)ws;            // 32768*16*8  = 4 MiB
    int*   jstar = (int*)(ws + (size_t)M_ROWS * 16 * 8);           // 128 KiB
    float* LS    = (float*)(ws + (size_t)M_ROWS * 16 * 8 + M_ROWS * 4); // 2 MiB

    float* Hbuf = out;  // stage H in d_out; overwritten by gather at the end

    // 1) H = relu(x @ W1^T + b1)
    gemm1_relu<<<dim3(H_DIM / BN, M_ROWS / BM), 256, 0, stream>>>(x, i2m_w, i2m_b, Hbuf);
    // 2) per-tile argmax of (H @ W2^T + b2)
    gemm2_argmax<<<dim3(C_DIM / BN, M_ROWS / BM), 256, 0, stream>>>(Hbuf, m2h_w, m2h_b, part);
    // 3) reduce partials -> jstar
    argmax_reduce<<<(M_ROWS + 255) / 256, 256, 0, stream>>>(part, jstar);
    // 4) log-softmax table over all 1024 possible winner columns
    ls_table<<<C_DIM, 256, 0, stream>>>(h2o_w, h2o_b, LS);
    // 5) out[m,:] = LS[jstar[m],:]
    gather_out<<<(M_ROWS * (O_DIM / 4)) / 256, 256, 0, stream>>>(jstar, LS, out);
}

// Round 2
// 538.623 us; speedup vs baseline: 2.3515x; 2.3515x over previous
//
#include <hip/hip_runtime.h>
#include <stdint.h>

// Problem sizes (fixed by reference)
#define T_DIM 4096
#define B_DIM 8
#define M_ROWS (T_DIM * B_DIM)   // 32768
#define I_DIM 256
#define H_DIM 512
#define C_DIM 1024
#define O_DIM 512

typedef __attribute__((ext_vector_type(8))) short bf16x8;
typedef __attribute__((ext_vector_type(4))) float f32x4;

// ---------------------------------------------------------------------------
// GEMM1 (fp32 VALU, unchanged from round 1): H = relu(X @ W1^T + b1)
// ---------------------------------------------------------------------------
#define BM 64
#define BN 64
#define BK 32
#define TM 4
#define TN 4
#define PAD 4

__global__ __launch_bounds__(256)
void gemm1_relu(const float* __restrict__ X, const float* __restrict__ W1,
                const float* __restrict__ b1, float* __restrict__ Hout) {
    __shared__ float As[BK][BM + PAD];
    __shared__ float Bs[BK][BN + PAD];
    const int tid = threadIdx.x;
    const int tx = tid & 15;
    const int ty = tid >> 4;
    const int mBase = blockIdx.y * BM;
    const int nBase = blockIdx.x * BN;

    float acc[TM][TN] = {};

    for (int k0 = 0; k0 < I_DIM; k0 += BK) {
        #pragma unroll
        for (int l = 0; l < 2; ++l) {
            int f = tid + l * 256;
            int row = f >> 3, kv = (f & 7) << 2;
            float4 v = *(const float4*)(X + (size_t)(mBase + row) * I_DIM + k0 + kv);
            As[kv + 0][row] = v.x; As[kv + 1][row] = v.y;
            As[kv + 2][row] = v.z; As[kv + 3][row] = v.w;
        }
        #pragma unroll
        for (int l = 0; l < 2; ++l) {
            int f = tid + l * 256;
            int row = f >> 3, kv = (f & 7) << 2;
            float4 v = *(const float4*)(W1 + (size_t)(nBase + row) * I_DIM + k0 + kv);
            Bs[kv + 0][row] = v.x; Bs[kv + 1][row] = v.y;
            Bs[kv + 2][row] = v.z; Bs[kv + 3][row] = v.w;
        }
        __syncthreads();
        #pragma unroll
        for (int k = 0; k < BK; ++k) {
            float a[TM], b[TN];
            *(float4*)a = *(const float4*)&As[k][ty * TM];
            *(float4*)b = *(const float4*)&Bs[k][tx * TN];
            #pragma unroll
            for (int i = 0; i < TM; ++i)
                #pragma unroll
                for (int j = 0; j < TN; ++j)
                    acc[i][j] = fmaf(a[i], b[j], acc[i][j]);
        }
        __syncthreads();
    }

    #pragma unroll
    for (int i = 0; i < TM; ++i) {
        int m = mBase + ty * TM + i;
        float4 o;
        float* po = &o.x;
        #pragma unroll
        for (int j = 0; j < TN; ++j) {
            float v = acc[i][j] + b1[nBase + tx * TN + j];
            po[j] = v > 0.f ? v : 0.f;
        }
        *(float4*)(Hout + (size_t)m * H_DIM + nBase + tx * TN) = o;
    }
}

// ---------------------------------------------------------------------------
// Exact 3-way bf16 split by truncation: x = hi + mid + lo + O(2^-24 |x|).
// Residuals are exact in fp32 (Sterbenz); all ops are cheap bit/VALU ops.
// ---------------------------------------------------------------------------
__device__ __forceinline__ void split3(float x, ushort& h, ushort& m, ushort& l) {
    unsigned xu = __float_as_uint(x);
    float fh = __uint_as_float(xu & 0xFFFF0000u);
    float r  = x - fh;
    unsigned ru = __float_as_uint(r);
    float fm = __uint_as_float(ru & 0xFFFF0000u);
    float r2 = r - fm;
    h = (ushort)(xu >> 16);
    m = (ushort)(ru >> 16);
    l = (ushort)(__float_as_uint(r2) >> 16);
}

// One-time split of W2 [1024,512] fp32 -> 3 bf16 planes in ws
__global__ __launch_bounds__(256)
void w2_split(const float* __restrict__ W2, ushort* __restrict__ hi,
              ushort* __restrict__ mi, ushort* __restrict__ lo) {
    int i = (blockIdx.x * 256 + threadIdx.x) * 4;
    float4 v = *(const float4*)(W2 + i);
    ushort h[4], m[4], l[4];
    split3(v.x, h[0], m[0], l[0]);
    split3(v.y, h[1], m[1], l[1]);
    split3(v.z, h[2], m[2], l[2]);
    split3(v.w, h[3], m[3], l[3]);
    *(ushort4*)(hi + i) = make_ushort4(h[0], h[1], h[2], h[3]);
    *(ushort4*)(mi + i) = make_ushort4(m[0], m[1], m[2], m[3]);
    *(ushort4*)(lo + i) = make_ushort4(l[0], l[1], l[2], l[3]);
}

// Monotone packing: larger packed <=> (larger value, then smaller col index)
__device__ __forceinline__ unsigned long long packvi(float v, int col) {
    unsigned u = __float_as_uint(v);
    u = (u & 0x80000000u) ? ~u : (u | 0x80000000u);
    return ((unsigned long long)u << 32) | (unsigned)(~col);
}

// ---------------------------------------------------------------------------
// GEMM2 via bf16x3 MFMA + fused per-tile argmax.
// c[m,n] = sum_k H[m,k]*W2[n,k] + b2[n]; writes part[m*8 + nblock].
// Tile: 128x128x32, 4 waves in 2x2, each wave 4x4 tiles of 16x16x32.
// LDS rows padded to 40 ushorts (stride 80B): start bank-group = (5*row+q)&7
// covers all 8 groups per 8-lane cluster -> conflict-free ds_read_b128.
// ---------------------------------------------------------------------------
#define G2_BM 128
#define G2_BN 128
#define G2_BK 32
#define LDSW 40   // padded row stride in ushorts

__global__ __launch_bounds__(256)
void gemm2_mfma(const float* __restrict__ Hin,
                const ushort* __restrict__ W2h, const ushort* __restrict__ W2m,
                const ushort* __restrict__ W2l,
                const float* __restrict__ b2,
                unsigned long long* __restrict__ part) {
    __shared__ __align__(16) ushort Ah[3][G2_BM * LDSW];  // 30720 B
    __shared__ __align__(16) ushort Bh[3][G2_BN * LDSW];  // 30720 B

    const int tid  = threadIdx.x;
    const int lane = tid & 63;
    const int wave = tid >> 6;
    const int wm = wave >> 1, wn = wave & 1;
    const int lcol = lane & 15, quad = lane >> 4;
    const int mBase = blockIdx.y * G2_BM;
    const int nBase = blockIdx.x * G2_BN;

    // staging decomposition
    const int s_row  = tid >> 1;       // 0..127
    const int s_half = tid & 1;        // 0..1  (16 elements each)
    const ushort* w2p[3] = { W2h, W2m, W2l };

    f32x4 acc[4][4];
    #pragma unroll
    for (int i = 0; i < 4; ++i)
        #pragma unroll
        for (int j = 0; j < 4; ++j)
            acc[i][j] = (f32x4){0.f, 0.f, 0.f, 0.f};

    // fragment LDS offsets (ushort units)
    int aoff[4], boff[4];
    #pragma unroll
    for (int t = 0; t < 4; ++t) {
        aoff[t] = (wm * 64 + t * 16 + lcol) * LDSW + quad * 8;
        boff[t] = (wn * 64 + t * 16 + lcol) * LDSW + quad * 8;
    }

    for (int ks = 0; ks < H_DIM / G2_BK; ++ks) {
        const int k0 = ks * G2_BK;

        // ---- issue global loads into registers ----
        const float* asrc = Hin + (size_t)(mBase + s_row) * H_DIM + k0 + s_half * 16;
        float4 av0 = ((const float4*)asrc)[0];
        float4 av1 = ((const float4*)asrc)[1];
        float4 av2 = ((const float4*)asrc)[2];
        float4 av3 = ((const float4*)asrc)[3];

        uint4 bv[3][2];
        #pragma unroll
        for (int p = 0; p < 3; ++p) {
            const ushort* bsrc = w2p[p] + (size_t)(nBase + s_row) * H_DIM + k0 + s_half * 16;
            bv[p][0] = ((const uint4*)bsrc)[0];
            bv[p][1] = ((const uint4*)bsrc)[1];
        }

        __syncthreads();   // previous iteration's LDS reads complete

        // ---- convert A to 3 bf16 planes, write LDS ----
        {
            float f[16];
            *(float4*)&f[0]  = av0; *(float4*)&f[4]  = av1;
            *(float4*)&f[8]  = av2; *(float4*)&f[12] = av3;
            bf16x8 vh[2], vm[2], vl[2];
            #pragma unroll
            for (int j = 0; j < 16; ++j) {
                ushort h, m, l;
                split3(f[j], h, m, l);
                vh[j >> 3][j & 7] = (short)h;
                vm[j >> 3][j & 7] = (short)m;
                vl[j >> 3][j & 7] = (short)l;
            }
            int dst = s_row * LDSW + s_half * 16;
            *(bf16x8*)&Ah[0][dst] = vh[0]; *(bf16x8*)&Ah[0][dst + 8] = vh[1];
            *(bf16x8*)&Ah[1][dst] = vm[0]; *(bf16x8*)&Ah[1][dst + 8] = vm[1];
            *(bf16x8*)&Ah[2][dst] = vl[0]; *(bf16x8*)&Ah[2][dst + 8] = vl[1];
            #pragma unroll
            for (int p = 0; p < 3; ++p) {
                *(uint4*)&Bh[p][dst]     = bv[p][0];
                *(uint4*)&Bh[p][dst + 8] = bv[p][1];
            }
        }

        __syncthreads();

        // ---- fragments + 6-product MFMA chain ----
        bf16x8 af[4][3];
        #pragma unroll
        for (int mt = 0; mt < 4; ++mt)
            #pragma unroll
            for (int p = 0; p < 3; ++p)
                af[mt][p] = *(const bf16x8*)&Ah[p][aoff[mt]];

        #pragma unroll
        for (int nt = 0; nt < 4; ++nt) {
            bf16x8 bf[3];
            #pragma unroll
            for (int p = 0; p < 3; ++p)
                bf[p] = *(const bf16x8*)&Bh[p][boff[nt]];
            #pragma unroll
            for (int mt = 0; mt < 4; ++mt) {
                f32x4 a = acc[mt][nt];
                // smallest terms first; all products to 2^-16 order kept
                a = __builtin_amdgcn_mfma_f32_16x16x32_bf16(af[mt][2], bf[0], a, 0, 0, 0); // lo*hi
                a = __builtin_amdgcn_mfma_f32_16x16x32_bf16(af[mt][1], bf[1], a, 0, 0, 0); // mid*mid
                a = __builtin_amdgcn_mfma_f32_16x16x32_bf16(af[mt][0], bf[2], a, 0, 0, 0); // hi*lo
                a = __builtin_amdgcn_mfma_f32_16x16x32_bf16(af[mt][1], bf[0], a, 0, 0, 0); // mid*hi
                a = __builtin_amdgcn_mfma_f32_16x16x32_bf16(af[mt][0], bf[1], a, 0, 0, 0); // hi*mid
                a = __builtin_amdgcn_mfma_f32_16x16x32_bf16(af[mt][0], bf[0], a, 0, 0, 0); // hi*hi
                acc[mt][nt] = a;
            }
        }
    }

    // ---- epilogue: bias + per-row argmax over this 128-col block ----
    // D layout: row = quad*4 + r (+ wm*64 + mt*16), col = lcol (+ wn*64 + nt*16)
    unsigned long long best[4][4];
    #pragma unroll
    for (int mt = 0; mt < 4; ++mt)
        #pragma unroll
        for (int r = 0; r < 4; ++r)
            best[mt][r] = 0ull;

    #pragma unroll
    for (int nt = 0; nt < 4; ++nt) {
        int col = nBase + wn * 64 + nt * 16 + lcol;
        float bias = b2[col];
        #pragma unroll
        for (int mt = 0; mt < 4; ++mt) {
            #pragma unroll
            for (int r = 0; r < 4; ++r) {
                float v = acc[mt][nt][r] + bias;
                unsigned long long p = packvi(v, col);
                if (p > best[mt][r]) best[mt][r] = p;
            }
        }
    }
    // butterfly across the 16 lanes of each quad (col reduction)
    #pragma unroll
    for (int mt = 0; mt < 4; ++mt)
        #pragma unroll
        for (int r = 0; r < 4; ++r) {
            unsigned long long b = best[mt][r];
            #pragma unroll
            for (int off = 1; off < 16; off <<= 1) {
                unsigned long long o = __shfl_xor((long long)b, off, 64);
                if (o > b) b = o;
            }
            best[mt][r] = b;
        }

    __syncthreads();   // done reading LDS tiles; reuse Ah as reduction buffer
    unsigned long long* red = (unsigned long long*)&Ah[0][0];  // [128][2]
    if (lcol == 0) {
        #pragma unroll
        for (int mt = 0; mt < 4; ++mt)
            #pragma unroll
            for (int r = 0; r < 4; ++r)
                red[(wm * 64 + mt * 16 + quad * 4 + r) * 2 + wn] = best[mt][r];
    }
    __syncthreads();
    if (tid < G2_BM) {
        unsigned long long a = red[tid * 2], b = red[tid * 2 + 1];
        part[(size_t)(mBase + tid) * 8 + blockIdx.x] = (a > b) ? a : b;
    }
}

// Reduce 8 tile-partials per row -> jstar
__global__ __launch_bounds__(256)
void argmax_reduce(const unsigned long long* __restrict__ part, int* __restrict__ jstar) {
    int m = blockIdx.x * blockDim.x + threadIdx.x;
    if (m >= M_ROWS) return;
    const unsigned long long* p = part + (size_t)m * 8;
    unsigned long long best = p[0];
    #pragma unroll
    for (int t = 1; t < 8; ++t) {
        unsigned long long q = p[t];
        if (q > best) best = q;
    }
    unsigned u = (unsigned)(best >> 32);
    float v = (u & 0x80000000u) ? __uint_as_float(u ^ 0x80000000u)
                                : __uint_as_float(~u);
    int col = (int)(~(unsigned)best) & (C_DIM - 1);
    jstar[m] = (v > 0.f) ? col : 0;
}

// LS[j, o] = log_softmax_o( Wo[o, j] + bo[o] )
__global__ __launch_bounds__(256)
void ls_table(const float* __restrict__ Wo, const float* __restrict__ bo,
              float* __restrict__ LS) {
    const int j = blockIdx.x;
    const int t = threadIdx.x;
    __shared__ float sred[4];

    float l0 = Wo[(size_t)t * C_DIM + j] + bo[t];
    float l1 = Wo[(size_t)(t + 256) * C_DIM + j] + bo[t + 256];

    float mx = fmaxf(l0, l1);
    #pragma unroll
    for (int off = 1; off < 64; off <<= 1)
        mx = fmaxf(mx, __shfl_xor(mx, off, 64));
    if ((t & 63) == 0) sred[t >> 6] = mx;
    __syncthreads();
    mx = fmaxf(fmaxf(sred[0], sred[1]), fmaxf(sred[2], sred[3]));
    __syncthreads();

    float s = expf(l0 - mx) + expf(l1 - mx);
    #pragma unroll
    for (int off = 1; off < 64; off <<= 1)
        s += __shfl_xor(s, off, 64);
    if ((t & 63) == 0) sred[t >> 6] = s;
    __syncthreads();
    s = sred[0] + sred[1] + sred[2] + sred[3];

    float lse = mx + logf(s);
    LS[(size_t)j * O_DIM + t] = l0 - lse;
    LS[(size_t)j * O_DIM + t + 256] = l1 - lse;
}

__global__ __launch_bounds__(256)
void gather_out(const int* __restrict__ jstar, const float* __restrict__ LS,
                float* __restrict__ out) {
    int idx = blockIdx.x * blockDim.x + threadIdx.x;
    int m = idx >> 7;
    int q = idx & 127;
    float4 v = ((const float4*)LS)[((size_t)jstar[m] << 7) + q];
    ((float4*)out)[idx] = v;
}

extern "C" void kernel_launch(void* const* d_in, const int* in_sizes, int n_in,
                              void* d_out, int out_size, void* d_ws, size_t ws_size,
                              hipStream_t stream) {
    const float* x     = (const float*)d_in[0];
    const float* i2m_w = (const float*)d_in[2];
    const float* i2m_b = (const float*)d_in[3];
    const float* m2h_w = (const float*)d_in[4];
    const float* m2h_b = (const float*)d_in[5];
    const float* h2o_w = (const float*)d_in[6];
    const float* h2o_b = (const float*)d_in[7];
    float* out = (float*)d_out;

    // ws layout (bytes):
    //   [0, 3MB)      W2 split planes (hi|mid|lo, 1MB each)  -- dead after gemm2
    //   [3MB, 5MB)    part: 32768*8 u64
    //   [5MB, 5.125MB) jstar
    //   [0, 2MB)      LS table (aliases W2 planes, written after gemm2)
    char* ws = (char*)d_ws;
    ushort* w2h = (ushort*)(ws);
    ushort* w2m = (ushort*)(ws + 1048576);
    ushort* w2l = (ushort*)(ws + 2097152);
    unsigned long long* part = (unsigned long long*)(ws + 3145728);
    int*   jstar = (int*)(ws + 5242880);
    float* LS    = (float*)(ws);

    float* Hbuf = out;  // stage H in d_out; overwritten by gather at the end

    gemm1_relu<<<dim3(H_DIM / BN, M_ROWS / BM), 256, 0, stream>>>(x, i2m_w, i2m_b, Hbuf);
    w2_split<<<C_DIM * H_DIM / 1024, 256, 0, stream>>>(m2h_w, w2h, w2m, w2l);
    gemm2_mfma<<<dim3(C_DIM / G2_BN, M_ROWS / G2_BM), 256, 0, stream>>>(
        Hbuf, w2h, w2m, w2l, m2h_b, part);
    argmax_reduce<<<M_ROWS / 256, 256, 0, stream>>>(part, jstar);
    ls_table<<<C_DIM, 256, 0, stream>>>(h2o_w, h2o_b, LS);
    gather_out<<<(M_ROWS * (O_DIM / 4)) / 256, 256, 0, stream>>>(jstar, LS, out);
}

// Round 3
// 280.855 us; speedup vs baseline: 4.5097x; 1.9178x over previous
//
#include <hip/hip_runtime.h>
#include <stdint.h>

#define M_ROWS 32768
#define I_DIM 256
#define H_DIM 512
#define C_DIM 1024
#define O_DIM 512

typedef __attribute__((ext_vector_type(8))) short bf16x8;
typedef __attribute__((ext_vector_type(4))) float f32x4;

// ---------------------------------------------------------------------------
// 2-plane RNE split: x = hi + mid + r2, |r2| <= 2^-18 |x|.
// ---------------------------------------------------------------------------
__device__ __forceinline__ ushort bf16_rne(float f) {
    unsigned u = __float_as_uint(f);
    unsigned r = u + 0x7FFFu + ((u >> 16) & 1u);
    return (ushort)(r >> 16);
}
__device__ __forceinline__ float bf16_f32(ushort h) {
    return __uint_as_float(((unsigned)h) << 16);
}
__device__ __forceinline__ void split2(float f, ushort& hi, ushort& mid) {
    hi = bf16_rne(f);
    mid = bf16_rne(f - bf16_f32(hi));
}

__device__ __forceinline__ void async_ld16(const void* g, void* l) {
    __builtin_amdgcn_global_load_lds(
        (const __attribute__((address_space(1))) void*)g,
        (__attribute__((address_space(3))) void*)l, 16, 0, 0);
}

// Monotone packing: larger packed <=> (larger value, then smaller col index)
__device__ __forceinline__ unsigned long long packvi(float v, int col) {
    unsigned u = __float_as_uint(v);
    u = (u & 0x80000000u) ? ~u : (u | 0x80000000u);
    return ((unsigned long long)u << 32) | (unsigned)(~col);
}

// Split a weight matrix into hi/mid bf16 planes (RNE)
__global__ __launch_bounds__(256)
void wsplit(const float* __restrict__ W, ushort* __restrict__ hi,
            ushort* __restrict__ mid) {
    int i = (blockIdx.x * 256 + threadIdx.x) * 4;
    float4 v = *(const float4*)(W + i);
    ushort4 hv, mv;
    split2(v.x, hv.x, mv.x);
    split2(v.y, hv.y, mv.y);
    split2(v.z, hv.z, mv.z);
    split2(v.w, hv.w, mv.w);
    *(ushort4*)(hi + i) = hv;
    *(ushort4*)(mid + i) = mv;
}

// ---------------------------------------------------------------------------
// GEMM1 (MFMA, 2-plane x 2-plane, 4 products):
// Hp[m,n] = pack_bf16x2( relu( sum_k X[m,k]*W1[n,k] + b1[n] ) )
// Block 128x128, BK=32, 4 waves (2x2), wave tile 64x64 as 4x4 of 16x16x32.
// ---------------------------------------------------------------------------
__global__ __launch_bounds__(256, 3)
void gemm1_mfma(const float* __restrict__ X, const ushort* __restrict__ W1h,
                const ushort* __restrict__ W1m, const float* __restrict__ b1,
                unsigned int* __restrict__ Hp) {
    __shared__ __align__(16) ushort As[2][128 * 32];
    __shared__ __align__(16) ushort Bs[2][128 * 32];
    const int tid = threadIdx.x;
    const int lane = tid & 63, wave = tid >> 6;
    const int wm = wave >> 1, wn = wave & 1;
    const int lcol = lane & 15, quad = lane >> 4;
    const int mBase = blockIdx.x * 128;   // x = M so same-A blocks share an XCD
    const int nBase = blockIdx.y * 128;
    const int s_row = tid >> 1, s_half = tid & 1;
    const int bplane = wave >> 1;
    const ushort* wp = bplane ? W1m : W1h;
    const int brow0 = (wave & 1) * 64;

    f32x4 acc[4][4];
    #pragma unroll
    for (int i = 0; i < 4; ++i)
        #pragma unroll
        for (int j = 0; j < 4; ++j)
            acc[i][j] = (f32x4){0.f, 0.f, 0.f, 0.f};

    int aoff[4], boff[4];
    #pragma unroll
    for (int t = 0; t < 4; ++t) {
        aoff[t] = (wm * 64 + t * 16 + lcol) * 32 + quad * 8;
        boff[t] = (wn * 64 + t * 16 + lcol) * 32 + quad * 8;
    }

    for (int ks = 0; ks < I_DIM / 32; ++ks) {
        const int k0 = ks * 32;
        // A global loads (registers; no LDS touch before barrier)
        const float* ap = X + (size_t)(mBase + s_row) * I_DIM + k0 + s_half * 16;
        float4 f0 = ((const float4*)ap)[0];
        float4 f1 = ((const float4*)ap)[1];
        float4 f2 = ((const float4*)ap)[2];
        float4 f3 = ((const float4*)ap)[3];

        __syncthreads();   // previous iteration's LDS reads complete

        // B planes: async global->LDS, natural [row][k] layout (64B rows)
        #pragma unroll
        for (int i = 0; i < 4; ++i) {
            int r = brow0 + i * 16;
            const ushort* g = wp + (size_t)(nBase + r + (lane >> 2)) * I_DIM
                              + k0 + (lane & 3) * 8;
            async_ld16(g, &Bs[bplane][r * 32]);
        }

        // A: split fp32 -> 2 bf16 planes, write LDS (parity-scheduled chunks)
        float f[16];
        *(float4*)&f[0] = f0; *(float4*)&f[4] = f1;
        *(float4*)&f[8] = f2; *(float4*)&f[12] = f3;
        bf16x8 h0, h1, m0, m1;
        #pragma unroll
        for (int j = 0; j < 8; ++j) {
            ushort hu, mu;
            split2(f[j], hu, mu);
            h0[j] = (short)hu; m0[j] = (short)mu;
            split2(f[j + 8], hu, mu);
            h1[j] = (short)hu; m1[j] = (short)mu;
        }
        int dst = s_row * 32 + s_half * 16;
        int sw = (s_row >> 1) & 1;
        *(bf16x8*)&As[0][dst + sw * 8]     = sw ? h1 : h0;
        *(bf16x8*)&As[0][dst + 8 - sw * 8] = sw ? h0 : h1;
        *(bf16x8*)&As[1][dst + sw * 8]     = sw ? m1 : m0;
        *(bf16x8*)&As[1][dst + 8 - sw * 8] = sw ? m0 : m1;

        __syncthreads();   // B DMA arrived (vmcnt) + A writes visible

        bf16x8 af[4][2];
        #pragma unroll
        for (int mt = 0; mt < 4; ++mt) {
            af[mt][0] = *(const bf16x8*)&As[0][aoff[mt]];
            af[mt][1] = *(const bf16x8*)&As[1][aoff[mt]];
        }
        #pragma unroll
        for (int nt = 0; nt < 4; ++nt) {
            bf16x8 bh = *(const bf16x8*)&Bs[0][boff[nt]];
            bf16x8 bm = *(const bf16x8*)&Bs[1][boff[nt]];
            #pragma unroll
            for (int mt = 0; mt < 4; ++mt) {
                f32x4 a = acc[mt][nt];
                a = __builtin_amdgcn_mfma_f32_16x16x32_bf16(af[mt][1], bm, a, 0, 0, 0);
                a = __builtin_amdgcn_mfma_f32_16x16x32_bf16(af[mt][1], bh, a, 0, 0, 0);
                a = __builtin_amdgcn_mfma_f32_16x16x32_bf16(af[mt][0], bm, a, 0, 0, 0);
                a = __builtin_amdgcn_mfma_f32_16x16x32_bf16(af[mt][0], bh, a, 0, 0, 0);
                acc[mt][nt] = a;
            }
        }
    }

    // epilogue: bias + relu + split2 -> packed u32 (hi<<16 | mid)
    #pragma unroll
    for (int nt = 0; nt < 4; ++nt) {
        int col = nBase + wn * 64 + nt * 16 + lcol;
        float bias = b1[col];
        #pragma unroll
        for (int mt = 0; mt < 4; ++mt) {
            #pragma unroll
            for (int r = 0; r < 4; ++r) {
                int row = mBase + wm * 64 + mt * 16 + quad * 4 + r;
                float v = fmaxf(acc[mt][nt][r] + bias, 0.f);
                ushort hu, mu;
                split2(v, hu, mu);
                Hp[(size_t)row * H_DIM + col] = ((unsigned)hu << 16) | (unsigned)mu;
            }
        }
    }
}

// ---------------------------------------------------------------------------
// GEMM2 (MFMA, 2x2 planes, 4 products) + fused per-tile argmax.
// A = packed H (unpack in staging), B = pre-split W2 planes via global_load_lds.
// ---------------------------------------------------------------------------
__global__ __launch_bounds__(256, 3)
void gemm2_mfma(const unsigned int* __restrict__ Hp,
                const ushort* __restrict__ W2h, const ushort* __restrict__ W2m,
                const float* __restrict__ b2,
                unsigned long long* __restrict__ part) {
    __shared__ __align__(16) ushort As[2][128 * 32];
    __shared__ __align__(16) ushort Bs[2][128 * 32];
    const int tid = threadIdx.x;
    const int lane = tid & 63, wave = tid >> 6;
    const int wm = wave >> 1, wn = wave & 1;
    const int lcol = lane & 15, quad = lane >> 4;
    const int mBase = blockIdx.x * 128;   // x = M: 8 n-blocks of one m-row share XCD L2
    const int nBase = blockIdx.y * 128;
    const int s_row = tid >> 1, s_half = tid & 1;
    const int bplane = wave >> 1;
    const ushort* wp = bplane ? W2m : W2h;
    const int brow0 = (wave & 1) * 64;

    f32x4 acc[4][4];
    #pragma unroll
    for (int i = 0; i < 4; ++i)
        #pragma unroll
        for (int j = 0; j < 4; ++j)
            acc[i][j] = (f32x4){0.f, 0.f, 0.f, 0.f};

    int aoff[4], boff[4];
    #pragma unroll
    for (int t = 0; t < 4; ++t) {
        aoff[t] = (wm * 64 + t * 16 + lcol) * 32 + quad * 8;
        boff[t] = (wn * 64 + t * 16 + lcol) * 32 + quad * 8;
    }

    for (int ks = 0; ks < H_DIM / 32; ++ks) {
        const int k0 = ks * 32;
        const unsigned int* ap = Hp + (size_t)(mBase + s_row) * H_DIM + k0 + s_half * 16;
        uint4 a0 = ((const uint4*)ap)[0];
        uint4 a1 = ((const uint4*)ap)[1];
        uint4 a2 = ((const uint4*)ap)[2];
        uint4 a3 = ((const uint4*)ap)[3];

        __syncthreads();

        #pragma unroll
        for (int i = 0; i < 4; ++i) {
            int r = brow0 + i * 16;
            const ushort* g = wp + (size_t)(nBase + r + (lane >> 2)) * H_DIM
                              + k0 + (lane & 3) * 8;
            async_ld16(g, &Bs[bplane][r * 32]);
        }

        // A: unpack packed (hi|mid) words into 2 planes
        unsigned int w[16];
        *(uint4*)&w[0] = a0;  *(uint4*)&w[4] = a1;
        *(uint4*)&w[8] = a2;  *(uint4*)&w[12] = a3;
        bf16x8 h0, h1, m0, m1;
        #pragma unroll
        for (int j = 0; j < 8; ++j) {
            h0[j] = (short)(w[j] >> 16);     m0[j] = (short)(w[j] & 0xFFFFu);
            h1[j] = (short)(w[j + 8] >> 16); m1[j] = (short)(w[j + 8] & 0xFFFFu);
        }
        int dst = s_row * 32 + s_half * 16;
        int sw = (s_row >> 1) & 1;
        *(bf16x8*)&As[0][dst + sw * 8]     = sw ? h1 : h0;
        *(bf16x8*)&As[0][dst + 8 - sw * 8] = sw ? h0 : h1;
        *(bf16x8*)&As[1][dst + sw * 8]     = sw ? m1 : m0;
        *(bf16x8*)&As[1][dst + 8 - sw * 8] = sw ? m0 : m1;

        __syncthreads();

        bf16x8 af[4][2];
        #pragma unroll
        for (int mt = 0; mt < 4; ++mt) {
            af[mt][0] = *(const bf16x8*)&As[0][aoff[mt]];
            af[mt][1] = *(const bf16x8*)&As[1][aoff[mt]];
        }
        #pragma unroll
        for (int nt = 0; nt < 4; ++nt) {
            bf16x8 bh = *(const bf16x8*)&Bs[0][boff[nt]];
            bf16x8 bm = *(const bf16x8*)&Bs[1][boff[nt]];
            #pragma unroll
            for (int mt = 0; mt < 4; ++mt) {
                f32x4 a = acc[mt][nt];
                a = __builtin_amdgcn_mfma_f32_16x16x32_bf16(af[mt][1], bm, a, 0, 0, 0);
                a = __builtin_amdgcn_mfma_f32_16x16x32_bf16(af[mt][1], bh, a, 0, 0, 0);
                a = __builtin_amdgcn_mfma_f32_16x16x32_bf16(af[mt][0], bm, a, 0, 0, 0);
                a = __builtin_amdgcn_mfma_f32_16x16x32_bf16(af[mt][0], bh, a, 0, 0, 0);
                acc[mt][nt] = a;
            }
        }
    }

    // ---- epilogue: bias + per-row argmax over this 128-col block ----
    unsigned long long best[4][4];
    #pragma unroll
    for (int mt = 0; mt < 4; ++mt)
        #pragma unroll
        for (int r = 0; r < 4; ++r)
            best[mt][r] = 0ull;

    #pragma unroll
    for (int nt = 0; nt < 4; ++nt) {
        int col = nBase + wn * 64 + nt * 16 + lcol;
        float bias = b2[col];
        #pragma unroll
        for (int mt = 0; mt < 4; ++mt) {
            #pragma unroll
            for (int r = 0; r < 4; ++r) {
                float v = acc[mt][nt][r] + bias;
                unsigned long long p = packvi(v, col);
                if (p > best[mt][r]) best[mt][r] = p;
            }
        }
    }
    #pragma unroll
    for (int mt = 0; mt < 4; ++mt)
        #pragma unroll
        for (int r = 0; r < 4; ++r) {
            unsigned long long b = best[mt][r];
            #pragma unroll
            for (int off = 1; off < 16; off <<= 1) {
                unsigned long long o = __shfl_xor((long long)b, off, 64);
                if (o > b) b = o;
            }
            best[mt][r] = b;
        }

    __syncthreads();
    unsigned long long* red = (unsigned long long*)&As[0][0];  // [128][2]
    if (lcol == 0) {
        #pragma unroll
        for (int mt = 0; mt < 4; ++mt)
            #pragma unroll
            for (int r = 0; r < 4; ++r)
                red[(wm * 64 + mt * 16 + quad * 4 + r) * 2 + wn] = best[mt][r];
    }
    __syncthreads();
    if (tid < 128) {
        unsigned long long a = red[tid * 2], b = red[tid * 2 + 1];
        part[(size_t)(mBase + tid) * 8 + blockIdx.y] = (a > b) ? a : b;
    }
}

// Reduce 8 tile-partials per row -> jstar
__global__ __launch_bounds__(256)
void argmax_reduce(const unsigned long long* __restrict__ part, int* __restrict__ jstar) {
    int m = blockIdx.x * blockDim.x + threadIdx.x;
    if (m >= M_ROWS) return;
    const unsigned long long* p = part + (size_t)m * 8;
    unsigned long long best = p[0];
    #pragma unroll
    for (int t = 1; t < 8; ++t) {
        unsigned long long q = p[t];
        if (q > best) best = q;
    }
    unsigned u = (unsigned)(best >> 32);
    float v = (u & 0x80000000u) ? __uint_as_float(u ^ 0x80000000u)
                                : __uint_as_float(~u);
    int col = (int)(~(unsigned)best) & (C_DIM - 1);
    jstar[m] = (v > 0.f) ? col : 0;
}

// LS[j, o] = log_softmax_o( Wo[o, j] + bo[o] )
__global__ __launch_bounds__(256)
void ls_table(const float* __restrict__ Wo, const float* __restrict__ bo,
              float* __restrict__ LS) {
    const int j = blockIdx.x;
    const int t = threadIdx.x;
    __shared__ float sred[4];

    float l0 = Wo[(size_t)t * C_DIM + j] + bo[t];
    float l1 = Wo[(size_t)(t + 256) * C_DIM + j] + bo[t + 256];

    float mx = fmaxf(l0, l1);
    #pragma unroll
    for (int off = 1; off < 64; off <<= 1)
        mx = fmaxf(mx, __shfl_xor(mx, off, 64));
    if ((t & 63) == 0) sred[t >> 6] = mx;
    __syncthreads();
    mx = fmaxf(fmaxf(sred[0], sred[1]), fmaxf(sred[2], sred[3]));
    __syncthreads();

    float s = expf(l0 - mx) + expf(l1 - mx);
    #pragma unroll
    for (int off = 1; off < 64; off <<= 1)
        s += __shfl_xor(s, off, 64);
    if ((t & 63) == 0) sred[t >> 6] = s;
    __syncthreads();
    s = sred[0] + sred[1] + sred[2] + sred[3];

    float lse = mx + logf(s);
    LS[(size_t)j * O_DIM + t] = l0 - lse;
    LS[(size_t)j * O_DIM + t + 256] = l1 - lse;
}

__global__ __launch_bounds__(256)
void gather_out(const int* __restrict__ jstar, const float* __restrict__ LS,
                float* __restrict__ out) {
    int idx = blockIdx.x * blockDim.x + threadIdx.x;
    int m = idx >> 7;
    int q = idx & 127;
    float4 v = ((const float4*)LS)[((size_t)jstar[m] << 7) + q];
    ((float4*)out)[idx] = v;
}

extern "C" void kernel_launch(void* const* d_in, const int* in_sizes, int n_in,
                              void* d_out, int out_size, void* d_ws, size_t ws_size,
                              hipStream_t stream) {
    const float* x     = (const float*)d_in[0];
    const float* i2m_w = (const float*)d_in[2];
    const float* i2m_b = (const float*)d_in[3];
    const float* m2h_w = (const float*)d_in[4];
    const float* m2h_b = (const float*)d_in[5];
    const float* h2o_w = (const float*)d_in[6];
    const float* h2o_b = (const float*)d_in[7];
    float* out = (float*)d_out;

    // ws layout (bytes):
    //   [0, 256K)        w1 hi plane   (dead after gemm1)
    //   [256K, 512K)     w1 mid plane
    //   [512K, 1.5M)     w2 hi plane   (dead after gemm2)
    //   [1.5M, 2.5M)     w2 mid plane
    //   [2.5M, 4.5M)     part: 32768*8 u64
    //   [4.5M, 4.625M)   jstar
    //   [0, 2M)          LS table (aliases weight planes, written after gemm2)
    char* ws = (char*)d_ws;
    ushort* w1h = (ushort*)(ws);
    ushort* w1m = (ushort*)(ws + 262144);
    ushort* w2h = (ushort*)(ws + 524288);
    ushort* w2m = (ushort*)(ws + 1572864);
    unsigned long long* part = (unsigned long long*)(ws + 2621440);
    int*   jstar = (int*)(ws + 4718592);
    float* LS    = (float*)(ws);

    unsigned int* Hp = (unsigned int*)d_out;  // packed H planes; overwritten by gather

    wsplit<<<(H_DIM * I_DIM) / 1024, 256, 0, stream>>>(i2m_w, w1h, w1m);
    wsplit<<<(C_DIM * H_DIM) / 1024, 256, 0, stream>>>(m2h_w, w2h, w2m);
    gemm1_mfma<<<dim3(M_ROWS / 128, H_DIM / 128), 256, 0, stream>>>(
        x, w1h, w1m, i2m_b, Hp);
    gemm2_mfma<<<dim3(M_ROWS / 128, C_DIM / 128), 256, 0, stream>>>(
        Hp, w2h, w2m, m2h_b, part);
    argmax_reduce<<<M_ROWS / 256, 256, 0, stream>>>(part, jstar);
    ls_table<<<C_DIM, 256, 0, stream>>>(h2o_w, h2o_b, LS);
    gather_out<<<(M_ROWS * (O_DIM / 4)) / 256, 256, 0, stream>>>(jstar, LS, out);
}

// Round 4
// 260.365 us; speedup vs baseline: 4.8646x; 1.0787x over previous
//
#include <hip/hip_runtime.h>
#include <stdint.h>

#define M_ROWS 32768
#define I_DIM 256
#define H_DIM 512
#define C_DIM 1024
#define O_DIM 512

typedef __attribute__((ext_vector_type(8))) short bf16x8;
typedef __attribute__((ext_vector_type(4))) float f32x4;

// ---------------------------------------------------------------------------
// 2-plane RNE split: x = hi + mid + r2, |r2| <= 2^-18 |x|.
// ---------------------------------------------------------------------------
__device__ __forceinline__ ushort bf16_rne(float f) {
    unsigned u = __float_as_uint(f);
    unsigned r = u + 0x7FFFu + ((u >> 16) & 1u);
    return (ushort)(r >> 16);
}
__device__ __forceinline__ float bf16_f32(ushort h) {
    return __uint_as_float(((unsigned)h) << 16);
}
__device__ __forceinline__ void split2(float f, ushort& hi, ushort& mid) {
    hi = bf16_rne(f);
    mid = bf16_rne(f - bf16_f32(hi));
}

__device__ __forceinline__ void async_ld16(const void* g, void* l) {
    __builtin_amdgcn_global_load_lds(
        (const __attribute__((address_space(1))) void*)g,
        (__attribute__((address_space(3))) void*)l, 16, 0, 0);
}

// Monotone packing: larger packed <=> (larger value, then smaller col index)
__device__ __forceinline__ unsigned long long packvi(float v, int col) {
    unsigned u = __float_as_uint(v);
    u = (u & 0x80000000u) ? ~u : (u | 0x80000000u);
    return ((unsigned long long)u << 32) | (unsigned)(~col);
}

// ---------------------------------------------------------------------------
// prep: fused weight splits + log-softmax table + part[] zeroing (all
// independent of the GEMMs; one launch instead of four).
//   blocks [0,128)     : W1 split  (512x256 = 131072 elems)
//   blocks [128,640)   : W2 split  (1024x512 = 524288 elems)
//   blocks [640,1664)  : LS[j,o] = log_softmax_o(Wo[o,j] + bo[o]), j = b-640
//   blocks [1664,1792) : part[] = 0
// ---------------------------------------------------------------------------
__global__ __launch_bounds__(256)
void prep(const float* __restrict__ W1, ushort* __restrict__ w1h, ushort* __restrict__ w1m,
          const float* __restrict__ W2, ushort* __restrict__ w2h, ushort* __restrict__ w2m,
          const float* __restrict__ Wo, const float* __restrict__ bo,
          float* __restrict__ LS, unsigned long long* __restrict__ part) {
    __shared__ float sred[4];
    const int b = blockIdx.x;
    const int t = threadIdx.x;
    if (b < 640) {
        const float* W = (b < 128) ? W1 : W2;
        ushort* hh = (b < 128) ? w1h : w2h;
        ushort* mm = (b < 128) ? w1m : w2m;
        int i = ((b < 128 ? b : b - 128) * 256 + t) * 4;
        float4 v = *(const float4*)(W + i);
        ushort4 hv, mv;
        split2(v.x, hv.x, mv.x);
        split2(v.y, hv.y, mv.y);
        split2(v.z, hv.z, mv.z);
        split2(v.w, hv.w, mv.w);
        *(ushort4*)(hh + i) = hv;
        *(ushort4*)(mm + i) = mv;
    } else if (b < 1664) {
        const int j = b - 640;
        float l0 = Wo[(size_t)t * C_DIM + j] + bo[t];
        float l1 = Wo[(size_t)(t + 256) * C_DIM + j] + bo[t + 256];

        float mx = fmaxf(l0, l1);
        #pragma unroll
        for (int off = 1; off < 64; off <<= 1)
            mx = fmaxf(mx, __shfl_xor(mx, off, 64));
        if ((t & 63) == 0) sred[t >> 6] = mx;
        __syncthreads();
        mx = fmaxf(fmaxf(sred[0], sred[1]), fmaxf(sred[2], sred[3]));
        __syncthreads();

        float s = expf(l0 - mx) + expf(l1 - mx);
        #pragma unroll
        for (int off = 1; off < 64; off <<= 1)
            s += __shfl_xor(s, off, 64);
        if ((t & 63) == 0) sred[t >> 6] = s;
        __syncthreads();
        s = sred[0] + sred[1] + sred[2] + sred[3];

        float lse = mx + logf(s);
        LS[(size_t)j * O_DIM + t] = l0 - lse;
        LS[(size_t)j * O_DIM + t + 256] = l1 - lse;
    } else {
        part[(b - 1664) * 256 + t] = 0ull;
    }
}

// ---------------------------------------------------------------------------
// GEMM1 (MFMA, 3 products): H = relu(X @ W1^T + b1), output as two bf16
// planes Hh/Hm so gemm2 can DMA-stage A. Block 128x128, BK=32, waves 2x2.
// ---------------------------------------------------------------------------
__global__ __launch_bounds__(256, 4)
void gemm1_mfma(const float* __restrict__ X, const ushort* __restrict__ W1h,
                const ushort* __restrict__ W1m, const float* __restrict__ b1,
                ushort* __restrict__ Hh, ushort* __restrict__ Hm) {
    __shared__ __align__(16) ushort As[2][128 * 32];
    __shared__ __align__(16) ushort Bs[2][128 * 32];
    const int tid = threadIdx.x;
    const int lane = tid & 63, wave = tid >> 6;
    const int wm = wave >> 1, wn = wave & 1;
    const int lcol = lane & 15, quad = lane >> 4;
    const int mBase = blockIdx.x * 128;
    const int nBase = blockIdx.y * 128;
    const int s_row = tid >> 1, s_half = tid & 1;
    const int bplane = wave >> 1;
    const ushort* wp = bplane ? W1m : W1h;
    const int brow0 = (wave & 1) * 64;
    const int lrow = lane >> 2, lk = (lane & 3) * 8;

    f32x4 acc[4][4];
    #pragma unroll
    for (int i = 0; i < 4; ++i)
        #pragma unroll
        for (int j = 0; j < 4; ++j)
            acc[i][j] = (f32x4){0.f, 0.f, 0.f, 0.f};

    int aoff[4], boff[4];
    #pragma unroll
    for (int t = 0; t < 4; ++t) {
        aoff[t] = (wm * 64 + t * 16 + lcol) * 32 + quad * 8;
        boff[t] = (wn * 64 + t * 16 + lcol) * 32 + quad * 8;
    }

    for (int ks = 0; ks < I_DIM / 32; ++ks) {
        const int k0 = ks * 32;
        const float* ap = X + (size_t)(mBase + s_row) * I_DIM + k0 + s_half * 16;
        float4 f0 = ((const float4*)ap)[0];
        float4 f1 = ((const float4*)ap)[1];
        float4 f2 = ((const float4*)ap)[2];
        float4 f3 = ((const float4*)ap)[3];

        __syncthreads();

        // B planes via DMA (each wave: one plane-half, 4 x 1KB)
        #pragma unroll
        for (int i = 0; i < 4; ++i) {
            int r = brow0 + i * 16;
            const ushort* g = wp + (size_t)(nBase + r + lrow) * I_DIM + k0 + lk;
            async_ld16(g, &Bs[bplane][r * 32]);
        }

        // A: split fp32 -> 2 bf16 planes, write LDS
        float f[16];
        *(float4*)&f[0] = f0; *(float4*)&f[4] = f1;
        *(float4*)&f[8] = f2; *(float4*)&f[12] = f3;
        bf16x8 h0, h1, m0, m1;
        #pragma unroll
        for (int j = 0; j < 8; ++j) {
            ushort hu, mu;
            split2(f[j], hu, mu);
            h0[j] = (short)hu; m0[j] = (short)mu;
            split2(f[j + 8], hu, mu);
            h1[j] = (short)hu; m1[j] = (short)mu;
        }
        int dst = s_row * 32 + s_half * 16;
        int sw = (s_row >> 1) & 1;
        *(bf16x8*)&As[0][dst + sw * 8]     = sw ? h1 : h0;
        *(bf16x8*)&As[0][dst + 8 - sw * 8] = sw ? h0 : h1;
        *(bf16x8*)&As[1][dst + sw * 8]     = sw ? m1 : m0;
        *(bf16x8*)&As[1][dst + 8 - sw * 8] = sw ? m0 : m1;

        __syncthreads();

        bf16x8 af[4][2];
        #pragma unroll
        for (int mt = 0; mt < 4; ++mt) {
            af[mt][0] = *(const bf16x8*)&As[0][aoff[mt]];
            af[mt][1] = *(const bf16x8*)&As[1][aoff[mt]];
        }
        #pragma unroll
        for (int nt = 0; nt < 4; ++nt) {
            bf16x8 bh = *(const bf16x8*)&Bs[0][boff[nt]];
            bf16x8 bm = *(const bf16x8*)&Bs[1][boff[nt]];
            #pragma unroll
            for (int mt = 0; mt < 4; ++mt) {
                f32x4 a = acc[mt][nt];
                a = __builtin_amdgcn_mfma_f32_16x16x32_bf16(af[mt][1], bh, a, 0, 0, 0);
                a = __builtin_amdgcn_mfma_f32_16x16x32_bf16(af[mt][0], bm, a, 0, 0, 0);
                a = __builtin_amdgcn_mfma_f32_16x16x32_bf16(af[mt][0], bh, a, 0, 0, 0);
                acc[mt][nt] = a;
            }
        }
    }

    // epilogue: bias + relu + split2 -> two ushort planes
    #pragma unroll
    for (int nt = 0; nt < 4; ++nt) {
        int col = nBase + wn * 64 + nt * 16 + lcol;
        float bias = b1[col];
        #pragma unroll
        for (int mt = 0; mt < 4; ++mt) {
            #pragma unroll
            for (int r = 0; r < 4; ++r) {
                int row = mBase + wm * 64 + mt * 16 + quad * 4 + r;
                float v = fmaxf(acc[mt][nt][r] + bias, 0.f);
                ushort hu, mu;
                split2(v, hu, mu);
                Hh[(size_t)row * H_DIM + col] = hu;
                Hm[(size_t)row * H_DIM + col] = mu;
            }
        }
    }
}

// ---------------------------------------------------------------------------
// GEMM2 (MFMA, 3 products, ALL-DMA staging) + fused argmax via atomicMax.
// Each wave DMA-stages exactly one 8KB plane buffer (A-hi/A-mid/B-hi/B-mid).
// ---------------------------------------------------------------------------
__global__ __launch_bounds__(256, 4)
void gemm2_mfma(const ushort* __restrict__ Hh, const ushort* __restrict__ Hm,
                const ushort* __restrict__ W2h, const ushort* __restrict__ W2m,
                const float* __restrict__ b2,
                unsigned long long* __restrict__ part) {
    __shared__ __align__(16) ushort As[2][128 * 32];
    __shared__ __align__(16) ushort Bs[2][128 * 32];
    const int tid = threadIdx.x;
    const int lane = tid & 63, wave = tid >> 6;
    const int wm = wave >> 1, wn = wave & 1;
    const int lcol = lane & 15, quad = lane >> 4;
    const int mBase = blockIdx.x * 128;
    const int nBase = blockIdx.y * 128;
    const int lrow = lane >> 2, lk = (lane & 3) * 8;

    // wave -> (global plane, LDS buffer) 1:1
    const ushort* gsrc;
    ushort* lbase;
    switch (wave) {
        case 0: gsrc = Hh  + (size_t)mBase * H_DIM; lbase = As[0]; break;
        case 1: gsrc = Hm  + (size_t)mBase * H_DIM; lbase = As[1]; break;
        case 2: gsrc = W2h + (size_t)nBase * H_DIM; lbase = Bs[0]; break;
        default: gsrc = W2m + (size_t)nBase * H_DIM; lbase = Bs[1]; break;
    }

    f32x4 acc[4][4];
    #pragma unroll
    for (int i = 0; i < 4; ++i)
        #pragma unroll
        for (int j = 0; j < 4; ++j)
            acc[i][j] = (f32x4){0.f, 0.f, 0.f, 0.f};

    int aoff[4], boff[4];
    #pragma unroll
    for (int t = 0; t < 4; ++t) {
        aoff[t] = (wm * 64 + t * 16 + lcol) * 32 + quad * 8;
        boff[t] = (wn * 64 + t * 16 + lcol) * 32 + quad * 8;
    }

    for (int ks = 0; ks < H_DIM / 32; ++ks) {
        const int k0 = ks * 32;
        __syncthreads();   // previous iteration's LDS reads complete
        #pragma unroll
        for (int j = 0; j < 8; ++j) {
            const ushort* g = gsrc + (size_t)(j * 16 + lrow) * H_DIM + k0 + lk;
            async_ld16(g, lbase + j * 512);
        }
        __syncthreads();   // DMA arrived (vmcnt drained by barrier)

        bf16x8 af[4][2];
        #pragma unroll
        for (int mt = 0; mt < 4; ++mt) {
            af[mt][0] = *(const bf16x8*)&As[0][aoff[mt]];
            af[mt][1] = *(const bf16x8*)&As[1][aoff[mt]];
        }
        #pragma unroll
        for (int nt = 0; nt < 4; ++nt) {
            bf16x8 bh = *(const bf16x8*)&Bs[0][boff[nt]];
            bf16x8 bm = *(const bf16x8*)&Bs[1][boff[nt]];
            #pragma unroll
            for (int mt = 0; mt < 4; ++mt) {
                f32x4 a = acc[mt][nt];
                a = __builtin_amdgcn_mfma_f32_16x16x32_bf16(af[mt][1], bh, a, 0, 0, 0);
                a = __builtin_amdgcn_mfma_f32_16x16x32_bf16(af[mt][0], bm, a, 0, 0, 0);
                a = __builtin_amdgcn_mfma_f32_16x16x32_bf16(af[mt][0], bh, a, 0, 0, 0);
                acc[mt][nt] = a;
            }
        }
    }

    // ---- epilogue: bias + argmax over this 128-col block -> atomicMax ----
    #pragma unroll
    for (int mt = 0; mt < 4; ++mt) {
        #pragma unroll
        for (int r = 0; r < 4; ++r) {
            unsigned long long best = 0ull;
            #pragma unroll
            for (int nt = 0; nt < 4; ++nt) {
                int col = nBase + wn * 64 + nt * 16 + lcol;
                float v = acc[mt][nt][r] + b2[col];
                unsigned long long p = packvi(v, col);
                if (p > best) best = p;
            }
            #pragma unroll
            for (int off = 1; off < 16; off <<= 1) {
                unsigned long long o = __shfl_xor((long long)best, off, 64);
                if (o > best) best = o;
            }
            if (lcol == 0) {
                int row = mBase + wm * 64 + mt * 16 + quad * 4 + r;
                atomicMax(&part[row], best);
            }
        }
    }
}

// out[row,:] = LS[jstar(part[row]), :]; 2 rows per block
__global__ __launch_bounds__(256)
void gather_out(const unsigned long long* __restrict__ part,
                const float* __restrict__ LS, float* __restrict__ out) {
    const int tid = threadIdx.x;
    const int row = blockIdx.x * 2 + (tid >> 7);
    const int q = tid & 127;
    unsigned long long best = part[row];
    unsigned u = (unsigned)(best >> 32);
    float v = (u & 0x80000000u) ? __uint_as_float(u ^ 0x80000000u)
                                : __uint_as_float(~u);
    int col = (int)(~(unsigned)best) & (C_DIM - 1);
    int j = (v > 0.f) ? col : 0;   // all-nonpositive c => relu zeros => top_k picks 0
    float4 val = ((const float4*)LS)[(size_t)j * 128 + q];
    ((float4*)out)[(size_t)row * 128 + q] = val;
}

extern "C" void kernel_launch(void* const* d_in, const int* in_sizes, int n_in,
                              void* d_out, int out_size, void* d_ws, size_t ws_size,
                              hipStream_t stream) {
    const float* x     = (const float*)d_in[0];
    const float* i2m_w = (const float*)d_in[2];
    const float* i2m_b = (const float*)d_in[3];
    const float* m2h_w = (const float*)d_in[4];
    const float* m2h_b = (const float*)d_in[5];
    const float* h2o_w = (const float*)d_in[6];
    const float* h2o_b = (const float*)d_in[7];
    float* out = (float*)d_out;

    // ws layout (bytes):
    //   [0, 256K)        w1 hi plane
    //   [256K, 512K)     w1 mid plane
    //   [512K, 1.5M)     w2 hi plane
    //   [1.5M, 2.5M)     w2 mid plane
    //   [2.5M, 4.5M)     LS table (1024 x 512 fp32)
    //   [4.5M, 4.75M)    part: 32768 u64 (atomicMax targets, zeroed in prep)
    char* ws = (char*)d_ws;
    ushort* w1h = (ushort*)(ws);
    ushort* w1m = (ushort*)(ws + 262144);
    ushort* w2h = (ushort*)(ws + 524288);
    ushort* w2m = (ushort*)(ws + 1572864);
    float*  LS  = (float*)(ws + 2621440);
    unsigned long long* part = (unsigned long long*)(ws + 4718592);

    // H planes live in d_out (2 x 32768*512 ushort = 64MB = exactly out_size*4B);
    // overwritten by gather_out at the end (gather reads only part + LS).
    ushort* Hh = (ushort*)d_out;
    ushort* Hm = Hh + (size_t)M_ROWS * H_DIM;

    prep<<<1792, 256, 0, stream>>>(i2m_w, w1h, w1m, m2h_w, w2h, w2m,
                                   h2o_w, h2o_b, LS, part);
    gemm1_mfma<<<dim3(M_ROWS / 128, H_DIM / 128), 256, 0, stream>>>(
        x, w1h, w1m, i2m_b, Hh, Hm);
    gemm2_mfma<<<dim3(M_ROWS / 128, C_DIM / 128), 256, 0, stream>>>(
        Hh, Hm, w2h, w2m, m2h_b, part);
    gather_out<<<M_ROWS / 2, 256, 0, stream>>>(part, LS, out);
}

// Round 5
// 253.453 us; speedup vs baseline: 4.9973x; 1.0273x over previous
//
#include <hip/hip_runtime.h>
#include <stdint.h>

#define M_ROWS 32768
#define I_DIM 256
#define H_DIM 512
#define C_DIM 1024
#define O_DIM 512

typedef __attribute__((ext_vector_type(8))) short bf16x8;
typedef __attribute__((ext_vector_type(4))) float f32x4;

// ---------------------------------------------------------------------------
// 2-plane RNE split: x = hi + mid + r2, |r2| <= 2^-18 |x|.
// ---------------------------------------------------------------------------
__device__ __forceinline__ ushort bf16_rne(float f) {
    unsigned u = __float_as_uint(f);
    unsigned r = u + 0x7FFFu + ((u >> 16) & 1u);
    return (ushort)(r >> 16);
}
__device__ __forceinline__ float bf16_f32(ushort h) {
    return __uint_as_float(((unsigned)h) << 16);
}
__device__ __forceinline__ void split2(float f, ushort& hi, ushort& mid) {
    hi = bf16_rne(f);
    mid = bf16_rne(f - bf16_f32(hi));
}

__device__ __forceinline__ void async_ld16(const void* g, void* l) {
    __builtin_amdgcn_global_load_lds(
        (const __attribute__((address_space(1))) void*)g,
        (__attribute__((address_space(3))) void*)l, 16, 0, 0);
}

// Monotone packing: larger packed <=> (larger value, then smaller col index)
__device__ __forceinline__ unsigned long long packvi(float v, int col) {
    unsigned u = __float_as_uint(v);
    u = (u & 0x80000000u) ? ~u : (u | 0x80000000u);
    return ((unsigned long long)u << 32) | (unsigned)(~col);
}

// Swizzle: within each 64B k32-group of a row, 16B chunk kc sits at slot
// (kc + (row>>1)) & 3. Makes stride-64B fragment ds_read_b128 conflict-free
// while keeping rows DMA-contiguous (global_load_lds can't pad).
__device__ __forceinline__ int slot_of(int kc, int row) {
    return (kc + ((row >> 1) & 3)) & 3;
}

// ---------------------------------------------------------------------------
// prep: weight splits (permuted layout) + log-softmax table + part[] zero.
//   blocks [0,64)      : W1 split   (512x256, 16384 chunks)
//   blocks [64,320)    : W2 split   (1024x512, 65536 chunks)
//   blocks [320,1344)  : LS[j,o] = log_softmax_o(Wo[o,j] + bo[o]), j = b-320
//   blocks [1344,1472) : part[] = 0
// ---------------------------------------------------------------------------
__global__ __launch_bounds__(256)
void prep(const float* __restrict__ W1, ushort* __restrict__ w1h, ushort* __restrict__ w1m,
          const float* __restrict__ W2, ushort* __restrict__ w2h, ushort* __restrict__ w2m,
          const float* __restrict__ Wo, const float* __restrict__ bo,
          float* __restrict__ LS, unsigned long long* __restrict__ part) {
    __shared__ float sred[4];
    const int b = blockIdx.x;
    const int t = threadIdx.x;
    if (b < 320) {
        const int isW1 = (b < 64);
        const float* W = isW1 ? W1 : W2;
        ushort* hh = isW1 ? w1h : w2h;
        ushort* mm = isW1 ? w1m : w2m;
        const int K = isW1 ? I_DIM : H_DIM;
        const int cpr = K >> 3;                       // chunks per row
        int gid = (isW1 ? b : b - 64) * 256 + t;      // chunk id
        int row = gid / cpr;
        int rem = gid - row * cpr;
        int g = rem >> 2, kc = rem & 3;
        float4 v0 = *(const float4*)(W + (size_t)gid * 8);
        float4 v1 = *(const float4*)(W + (size_t)gid * 8 + 4);
        __align__(16) ushort h[8], m[8];
        float f[8];
        *(float4*)&f[0] = v0; *(float4*)&f[4] = v1;
        #pragma unroll
        for (int j = 0; j < 8; ++j) split2(f[j], h[j], m[j]);
        size_t dst = (size_t)row * K + g * 32 + slot_of(kc, row) * 8;
        *(uint4*)(hh + dst) = *(uint4*)h;
        *(uint4*)(mm + dst) = *(uint4*)m;
    } else if (b < 1344) {
        const int j = b - 320;
        float l0 = Wo[(size_t)t * C_DIM + j] + bo[t];
        float l1 = Wo[(size_t)(t + 256) * C_DIM + j] + bo[t + 256];

        float mx = fmaxf(l0, l1);
        #pragma unroll
        for (int off = 1; off < 64; off <<= 1)
            mx = fmaxf(mx, __shfl_xor(mx, off, 64));
        if ((t & 63) == 0) sred[t >> 6] = mx;
        __syncthreads();
        mx = fmaxf(fmaxf(sred[0], sred[1]), fmaxf(sred[2], sred[3]));
        __syncthreads();

        float s = expf(l0 - mx) + expf(l1 - mx);
        #pragma unroll
        for (int off = 1; off < 64; off <<= 1)
            s += __shfl_xor(s, off, 64);
        if ((t & 63) == 0) sred[t >> 6] = s;
        __syncthreads();
        s = sred[0] + sred[1] + sred[2] + sred[3];

        float lse = mx + logf(s);
        LS[(size_t)j * O_DIM + t] = l0 - lse;
        LS[(size_t)j * O_DIM + t + 256] = l1 - lse;
    } else {
        part[(b - 1344) * 256 + t] = 0ull;
    }
}

// ---------------------------------------------------------------------------
// GEMM1 (MFMA, 3 products): H = relu(X @ W1^T + b1) -> two bf16 planes in
// permuted layout, stored via LDS-staged coalesced uint4 stores.
// ---------------------------------------------------------------------------
__global__ __launch_bounds__(256, 4)
void gemm1_mfma(const float* __restrict__ X, const ushort* __restrict__ W1h,
                const ushort* __restrict__ W1m, const float* __restrict__ b1,
                ushort* __restrict__ Hh, ushort* __restrict__ Hm) {
    __shared__ __align__(16) ushort LB[16384];   // 32KB: A planes, B planes / stage
    ushort* As0 = LB;
    ushort* As1 = LB + 4096;
    ushort* Bs0 = LB + 8192;
    ushort* Bs1 = LB + 12288;

    const int tid = threadIdx.x;
    const int lane = tid & 63, wave = tid >> 6;
    const int wm = wave >> 1, wn = wave & 1;
    const int lcol = lane & 15, quad = lane >> 4;
    const int mBase = blockIdx.x * 128;
    const int nBase = blockIdx.y * 128;
    const int s_row = tid >> 1, s_half = tid & 1;
    const int bplane = wave >> 1;
    const ushort* wp = bplane ? W1m : W1h;
    const int brow0 = (wave & 1) * 64;
    const int lrow = lane >> 2, lk = (lane & 3) * 8;

    f32x4 acc[4][4];
    #pragma unroll
    for (int i = 0; i < 4; ++i)
        #pragma unroll
        for (int j = 0; j < 4; ++j)
            acc[i][j] = (f32x4){0.f, 0.f, 0.f, 0.f};

    int aoff[4], boff[4];
    #pragma unroll
    for (int t = 0; t < 4; ++t) {
        int ra = wm * 64 + t * 16 + lcol;
        int rb = wn * 64 + t * 16 + lcol;
        aoff[t] = ra * 32 + slot_of(quad, ra) * 8;
        boff[t] = rb * 32 + slot_of(quad, rb) * 8;
    }
    // A staging write slots (chunks kc = s_half*2, s_half*2+1)
    const int sl0 = slot_of(s_half * 2,     s_row);
    const int sl1 = slot_of(s_half * 2 + 1, s_row);

    for (int ks = 0; ks < I_DIM / 32; ++ks) {
        const int k0 = ks * 32;
        const float* ap = X + (size_t)(mBase + s_row) * I_DIM + k0 + s_half * 16;
        float4 f0 = ((const float4*)ap)[0];
        float4 f1 = ((const float4*)ap)[1];
        float4 f2 = ((const float4*)ap)[2];
        float4 f3 = ((const float4*)ap)[3];

        __syncthreads();

        // B planes via DMA (permuted layout is already in the global buffers)
        #pragma unroll
        for (int i = 0; i < 4; ++i) {
            int r = brow0 + i * 16;
            const ushort* g = wp + (size_t)(nBase + r + lrow) * I_DIM + k0 + lk;
            async_ld16(g, (bplane ? Bs1 : Bs0) + r * 32);
        }

        // A: split fp32 -> 2 bf16 planes, swizzled LDS writes
        float f[16];
        *(float4*)&f[0] = f0; *(float4*)&f[4] = f1;
        *(float4*)&f[8] = f2; *(float4*)&f[12] = f3;
        bf16x8 h0, h1, m0, m1;
        #pragma unroll
        for (int j = 0; j < 8; ++j) {
            ushort hu, mu;
            split2(f[j], hu, mu);
            h0[j] = (short)hu; m0[j] = (short)mu;
            split2(f[j + 8], hu, mu);
            h1[j] = (short)hu; m1[j] = (short)mu;
        }
        *(bf16x8*)&As0[s_row * 32 + sl0 * 8] = h0;
        *(bf16x8*)&As0[s_row * 32 + sl1 * 8] = h1;
        *(bf16x8*)&As1[s_row * 32 + sl0 * 8] = m0;
        *(bf16x8*)&As1[s_row * 32 + sl1 * 8] = m1;

        __syncthreads();

        bf16x8 af[4][2];
        #pragma unroll
        for (int mt = 0; mt < 4; ++mt) {
            af[mt][0] = *(const bf16x8*)&As0[aoff[mt]];
            af[mt][1] = *(const bf16x8*)&As1[aoff[mt]];
        }
        #pragma unroll
        for (int nt = 0; nt < 4; ++nt) {
            bf16x8 bh = *(const bf16x8*)&Bs0[boff[nt]];
            bf16x8 bm = *(const bf16x8*)&Bs1[boff[nt]];
            #pragma unroll
            for (int mt = 0; mt < 4; ++mt) {
                f32x4 a = acc[mt][nt];
                a = __builtin_amdgcn_mfma_f32_16x16x32_bf16(af[mt][1], bh, a, 0, 0, 0);
                a = __builtin_amdgcn_mfma_f32_16x16x32_bf16(af[mt][0], bm, a, 0, 0, 0);
                a = __builtin_amdgcn_mfma_f32_16x16x32_bf16(af[mt][0], bh, a, 0, 0, 0);
                acc[mt][nt] = a;
            }
        }
    }

    // ---- epilogue: bias+relu+split, LDS-staged in permuted-global layout,
    //      then coalesced uint4 copies. Two passes (hi, mid); acc stays live.
    #pragma unroll
    for (int plane = 0; plane < 2; ++plane) {
        __syncthreads();   // previous LDS use complete
        #pragma unroll
        for (int nt = 0; nt < 4; ++nt) {
            int colRel = wn * 64 + nt * 16 + lcol;
            int g = colRel >> 5, kc = (colRel >> 3) & 3, pos = colRel & 7;
            float bias = b1[nBase + colRel];
            #pragma unroll
            for (int mt = 0; mt < 4; ++mt) {
                #pragma unroll
                for (int r = 0; r < 4; ++r) {
                    int rowRel = wm * 64 + mt * 16 + quad * 4 + r;
                    float v = fmaxf(acc[mt][nt][r] + bias, 0.f);
                    ushort hu, mu;
                    split2(v, hu, mu);
                    LB[rowRel * 128 + g * 32 + slot_of(kc, rowRel) * 8 + pos]
                        = plane ? mu : hu;
                }
            }
        }
        __syncthreads();
        ushort* dstp = plane ? Hm : Hh;
        #pragma unroll
        for (int l = 0; l < 8; ++l) {
            int c = l * 256 + tid;
            int row = c >> 4, idx = c & 15;
            *(uint4*)(dstp + (size_t)(mBase + row) * H_DIM + nBase + idx * 8)
                = *(const uint4*)&LB[row * 128 + idx * 8];
        }
    }
}

// ---------------------------------------------------------------------------
// GEMM2 (MFMA, 3 products, all-DMA staging, swizzled reads) + argmax atomicMax.
// ---------------------------------------------------------------------------
__global__ __launch_bounds__(256, 4)
void gemm2_mfma(const ushort* __restrict__ Hh, const ushort* __restrict__ Hm,
                const ushort* __restrict__ W2h, const ushort* __restrict__ W2m,
                const float* __restrict__ b2,
                unsigned long long* __restrict__ part) {
    __shared__ __align__(16) ushort As[2][128 * 32];
    __shared__ __align__(16) ushort Bs[2][128 * 32];
    const int tid = threadIdx.x;
    const int lane = tid & 63, wave = tid >> 6;
    const int wm = wave >> 1, wn = wave & 1;
    const int lcol = lane & 15, quad = lane >> 4;
    const int mBase = blockIdx.x * 128;
    const int nBase = blockIdx.y * 128;
    const int lrow = lane >> 2, lk = (lane & 3) * 8;

    const ushort* gsrc;
    ushort* lbase;
    switch (wave) {
        case 0: gsrc = Hh  + (size_t)mBase * H_DIM; lbase = As[0]; break;
        case 1: gsrc = Hm  + (size_t)mBase * H_DIM; lbase = As[1]; break;
        case 2: gsrc = W2h + (size_t)nBase * H_DIM; lbase = Bs[0]; break;
        default: gsrc = W2m + (size_t)nBase * H_DIM; lbase = Bs[1]; break;
    }

    f32x4 acc[4][4];
    #pragma unroll
    for (int i = 0; i < 4; ++i)
        #pragma unroll
        for (int j = 0; j < 4; ++j)
            acc[i][j] = (f32x4){0.f, 0.f, 0.f, 0.f};

    int aoff[4], boff[4];
    #pragma unroll
    for (int t = 0; t < 4; ++t) {
        int ra = wm * 64 + t * 16 + lcol;
        int rb = wn * 64 + t * 16 + lcol;
        aoff[t] = ra * 32 + slot_of(quad, ra) * 8;
        boff[t] = rb * 32 + slot_of(quad, rb) * 8;
    }

    for (int ks = 0; ks < H_DIM / 32; ++ks) {
        const int k0 = ks * 32;
        __syncthreads();
        #pragma unroll
        for (int j = 0; j < 8; ++j) {
            const ushort* g = gsrc + (size_t)(j * 16 + lrow) * H_DIM + k0 + lk;
            async_ld16(g, lbase + j * 512);
        }
        __syncthreads();

        bf16x8 af[4][2];
        #pragma unroll
        for (int mt = 0; mt < 4; ++mt) {
            af[mt][0] = *(const bf16x8*)&As[0][aoff[mt]];
            af[mt][1] = *(const bf16x8*)&As[1][aoff[mt]];
        }
        #pragma unroll
        for (int nt = 0; nt < 4; ++nt) {
            bf16x8 bh = *(const bf16x8*)&Bs[0][boff[nt]];
            bf16x8 bm = *(const bf16x8*)&Bs[1][boff[nt]];
            #pragma unroll
            for (int mt = 0; mt < 4; ++mt) {
                f32x4 a = acc[mt][nt];
                a = __builtin_amdgcn_mfma_f32_16x16x32_bf16(af[mt][1], bh, a, 0, 0, 0);
                a = __builtin_amdgcn_mfma_f32_16x16x32_bf16(af[mt][0], bm, a, 0, 0, 0);
                a = __builtin_amdgcn_mfma_f32_16x16x32_bf16(af[mt][0], bh, a, 0, 0, 0);
                acc[mt][nt] = a;
            }
        }
    }

    // ---- epilogue: bias + argmax over this 128-col block -> atomicMax ----
    #pragma unroll
    for (int mt = 0; mt < 4; ++mt) {
        #pragma unroll
        for (int r = 0; r < 4; ++r) {
            unsigned long long best = 0ull;
            #pragma unroll
            for (int nt = 0; nt < 4; ++nt) {
                int col = nBase + wn * 64 + nt * 16 + lcol;
                float v = acc[mt][nt][r] + b2[col];
                unsigned long long p = packvi(v, col);
                if (p > best) best = p;
            }
            #pragma unroll
            for (int off = 1; off < 16; off <<= 1) {
                unsigned long long o = __shfl_xor((long long)best, off, 64);
                if (o > best) best = o;
            }
            if (lcol == 0) {
                int row = mBase + wm * 64 + mt * 16 + quad * 4 + r;
                atomicMax(&part[row], best);
            }
        }
    }
}

// out[row,:] = LS[jstar(part[row]), :]; 2 rows per block
__global__ __launch_bounds__(256)
void gather_out(const unsigned long long* __restrict__ part,
                const float* __restrict__ LS, float* __restrict__ out) {
    const int tid = threadIdx.x;
    const int row = blockIdx.x * 2 + (tid >> 7);
    const int q = tid & 127;
    unsigned long long best = part[row];
    unsigned u = (unsigned)(best >> 32);
    float v = (u & 0x80000000u) ? __uint_as_float(u ^ 0x80000000u)
                                : __uint_as_float(~u);
    int col = (int)(~(unsigned)best) & (C_DIM - 1);
    int j = (v > 0.f) ? col : 0;   // all-nonpositive c => relu zeros => top_k picks 0
    float4 val = ((const float4*)LS)[(size_t)j * 128 + q];
    ((float4*)out)[(size_t)row * 128 + q] = val;
}

extern "C" void kernel_launch(void* const* d_in, const int* in_sizes, int n_in,
                              void* d_out, int out_size, void* d_ws, size_t ws_size,
                              hipStream_t stream) {
    const float* x     = (const float*)d_in[0];
    const float* i2m_w = (const float*)d_in[2];
    const float* i2m_b = (const float*)d_in[3];
    const float* m2h_w = (const float*)d_in[4];
    const float* m2h_b = (const float*)d_in[5];
    const float* h2o_w = (const float*)d_in[6];
    const float* h2o_b = (const float*)d_in[7];
    float* out = (float*)d_out;

    // ws layout (bytes):
    //   [0, 256K)        w1 hi plane   [256K, 512K)  w1 mid plane
    //   [512K, 1.5M)     w2 hi plane   [1.5M, 2.5M)  w2 mid plane
    //   [2.5M, 4.5M)     LS table (1024 x 512 fp32)
    //   [4.5M, 4.75M)    part: 32768 u64 (atomicMax targets, zeroed in prep)
    char* ws = (char*)d_ws;
    ushort* w1h = (ushort*)(ws);
    ushort* w1m = (ushort*)(ws + 262144);
    ushort* w2h = (ushort*)(ws + 524288);
    ushort* w2m = (ushort*)(ws + 1572864);
    float*  LS  = (float*)(ws + 2621440);
    unsigned long long* part = (unsigned long long*)(ws + 4718592);

    // H planes live in d_out (2 x 32768*512 ushort = 64MB = exactly out_size*4B)
    ushort* Hh = (ushort*)d_out;
    ushort* Hm = Hh + (size_t)M_ROWS * H_DIM;

    prep<<<1472, 256, 0, stream>>>(i2m_w, w1h, w1m, m2h_w, w2h, w2m,
                                   h2o_w, h2o_b, LS, part);
    gemm1_mfma<<<dim3(M_ROWS / 128, H_DIM / 128), 256, 0, stream>>>(
        x, w1h, w1m, i2m_b, Hh, Hm);
    gemm2_mfma<<<dim3(M_ROWS / 128, C_DIM / 128), 256, 0, stream>>>(
        Hh, Hm, w2h, w2m, m2h_b, part);
    gather_out<<<M_ROWS / 2, 256, 0, stream>>>(part, LS, out);
}